// Round 2
// 254.915 us; speedup vs baseline: 1.0552x; 1.0552x over previous
//
#include <hip/hip_runtime.h>

// Problem constants from the reference
static constexpr int B = 4096;
static constexpr int T = 200;
static constexpr int A = 64;
static constexpr int N = B * T;          // 819,200 gathered elements
static constexpr int BLOCK = 256;
static constexpr int VEC = 2;            // elements per thread
static constexpr int GRID1 = N / (BLOCK * VEC);   // 1600 blocks, exact

// loss = (1/B) * sum_{b,t} (ea[b]-adv[b]) * log(policies[b,t,actions[b,t]])
//
// Stage 1: flat partial sums, one partial per block -> ws[blockIdx].
// Layout choice: thread handles g = 2*tid and 2*tid+1. Per gather instruction,
// a wave's 64 lanes touch rows 2 apart -> 128 consecutive rows = 32 KB
// contiguous window (vs 1 MB before) for better DRAM page locality.
// 1600 blocks = 25 waves/CU (2x the previous TLP, 7/6 block imbalance vs 4/3).
__global__ __launch_bounds__(BLOCK) void multiloss_partial(
    const float* __restrict__ policies,   // [B*T*A]
    const int*   __restrict__ actions,    // [B*T] (int32; jax x64 disabled)
    const float* __restrict__ ea,         // [B]
    const float* __restrict__ adv,        // [B]
    float* __restrict__ ws)               // [GRID1] partials
{
    const int tid = blockIdx.x * BLOCK + threadIdx.x;
    const int g0  = tid * VEC;

    // coalesced 8B action load (nontemporal builtin requires scalar type:
    // load as long long, unpack the two int32s)
    const long long apair = __builtin_nontemporal_load(
        ((const long long*)actions) + tid);
    const int a0 = (int)(apair & 0xffffffffLL);
    const int a1 = (int)(apair >> 32);

    // issue both gathers before any use; streaming hint (each line used once)
    const float p0 = __builtin_nontemporal_load(
        policies + (size_t)g0 * A + a0);
    const float p1 = __builtin_nontemporal_load(
        policies + (size_t)(g0 + 1) * A + a1);

    // coef loads: ~8 distinct b per block -> L1/L2 broadcast hits
    const int b0 = g0 / T;                // magic-mul division (constant T)
    const int b1 = (g0 + 1) / T;
    const float c0 = ea[b0] - adv[b0];
    const float c1 = ea[b1] - adv[b1];

    float acc = __logf(p0) * c0 + __logf(p1) * c1;

    // wave (64-lane) butterfly reduction
    #pragma unroll
    for (int off = 32; off > 0; off >>= 1)
        acc += __shfl_down(acc, off, 64);

    __shared__ float red[4];
    const int lane = threadIdx.x & 63;
    const int wid  = threadIdx.x >> 6;
    if (lane == 0) red[wid] = acc;
    __syncthreads();
    if (threadIdx.x == 0)
        ws[blockIdx.x] = red[0] + red[1] + red[2] + red[3];
}

// Stage 2: one block reduces GRID1 partials, writes out[0] = total / B
__global__ __launch_bounds__(BLOCK) void multiloss_final(
    const float* __restrict__ ws,
    float* __restrict__ out)
{
    float acc = 0.0f;
    for (int i = threadIdx.x; i < GRID1; i += BLOCK)
        acc += ws[i];

    #pragma unroll
    for (int off = 32; off > 0; off >>= 1)
        acc += __shfl_down(acc, off, 64);

    __shared__ float red[4];
    const int lane = threadIdx.x & 63;
    const int wid  = threadIdx.x >> 6;
    if (lane == 0) red[wid] = acc;
    __syncthreads();
    if (threadIdx.x == 0)
        out[0] = (red[0] + red[1] + red[2] + red[3]) * (1.0f / (float)B);
}

extern "C" void kernel_launch(void* const* d_in, const int* in_sizes, int n_in,
                              void* d_out, int out_size, void* d_ws, size_t ws_size,
                              hipStream_t stream) {
    const float* policies = (const float*)d_in[0];
    const int*   actions  = (const int*)d_in[1];
    const float* ea       = (const float*)d_in[2];
    const float* adv      = (const float*)d_in[3];
    float* out = (float*)d_out;
    float* ws  = (float*)d_ws;

    multiloss_partial<<<GRID1, BLOCK, 0, stream>>>(policies, actions, ea, adv, ws);
    multiloss_final<<<1, BLOCK, 0, stream>>>(ws, out);
}